// Round 13
// baseline (1704.168 us; speedup 1.0000x reference)
//
#include <hip/hip_runtime.h>
#include <hip/hip_bf16.h>
#include <cstdint>
#include <cstddef>

using bf16 = __hip_bfloat16;
typedef __attribute__((ext_vector_type(8))) short bf16x8;
typedef __attribute__((ext_vector_type(4))) float f32x4;
typedef __attribute__((ext_vector_type(8))) unsigned short u16x8;

#define DEV static __device__ __forceinline__

DEV unsigned short f2bf(float f) {
    bf16 h = __float2bfloat16(f);
    return __builtin_bit_cast(unsigned short, h);
}

typedef const __attribute__((address_space(1))) void* as1cv;
typedef __attribute__((address_space(3))) void* as3v;

DEV void load_lds16(const void* g, void* l) {
    __builtin_amdgcn_global_load_lds((as1cv)g, (as3v)l, 16, 0, 0);
}

// ---------------------------------------------------------------------------
// Generic bf16 MFMA GEMM: C[M,N] = A[M,K] @ B^T  (B stored [N][K], k-contiguous)
// 128x128 tile, BK=64, 4 waves, 2-phase double-buffered LDS.
// EPI: 0 = store bf16; 1 = relu -> bf16;
//      3 = fp32 NT store, coalesced via padded-LDS transpose (logits);
//      5 = fp32 atomicAdd (split-K partials / residual accumulate).
// Ag2/ySplitA: blocks with by >= ySplitA read A from Ag2 (merged dual-source).
// Split-K: gridDim.z = Hdim = nchunks, aZ2/bZ2 = chunkK, Kdim = chunkK.
// ---------------------------------------------------------------------------
template<int EPI>
__global__ __launch_bounds__(256)
void gemm_k(const bf16* __restrict__ Ag, const bf16* __restrict__ Bg,
            void* __restrict__ Cg,
            int Mdim, int Ndim, int Kdim,
            int lda, int ldb, int ldc,
            int Hdim, long aZ1, long aZ2, long bZ1, long bZ2,
            long cZ1, long cZ2, float scale,
            const bf16* __restrict__ Ag2, int ySplitA)
{
    __shared__ __align__(16) char lds[67584];   // dbuf 2x32K; EPI3 reuses 128x132 f32

    const int t = threadIdx.x;
    const int wave = t >> 6, lane = t & 63;
    const int wr = wave >> 1, wc = wave & 1;
    const int lo = lane & 15, hi = lane >> 4;

    const int bx2 = blockIdx.x, by2 = blockIdx.y;
    const int m0 = bx2 * 128, n0 = by2 * 128;
    const int z = blockIdx.z;
    const int z1 = z / Hdim, z2 = z - z1 * Hdim;

    const bf16* Abase = (by2 >= ySplitA) ? Ag2 : Ag;
    const bf16* A = Abase + (size_t)z1 * aZ1 + (size_t)z2 * aZ2;
    const bf16* B = Bg + (size_t)z1 * bZ1 + (size_t)z2 * bZ2;

    f32x4 acc[4][4];
#pragma unroll
    for (int m = 0; m < 4; ++m)
#pragma unroll
        for (int n = 0; n < 4; ++n)
            acc[m][n] = f32x4{0.f, 0.f, 0.f, 0.f};

    const int nk = Kdim >> 6;

    auto stage = [&](int kt, int buf) {
        const int k0 = kt << 6;
        char* dA = lds + buf * 32768;
        char* dB = dA + 16384;
#pragma unroll
        for (int i = 0; i < 4; ++i) {
            int u = i * 256 + t;
            int row = u >> 3;
            int cb = (u & 7) ^ (row & 7);
            load_lds16(A + (size_t)(m0 + row) * lda + (k0 + cb * 8),
                       dA + i * 4096 + wave * 1024);
        }
#pragma unroll
        for (int i = 0; i < 4; ++i) {
            int u = i * 256 + t;
            int row = u >> 3;
            int cb = (u & 7) ^ (row & 7);
            load_lds16(B + (size_t)(n0 + row) * ldb + (k0 + cb * 8),
                       dB + i * 4096 + wave * 1024);
        }
    };

    stage(0, 0);
    int cur = 0;
    for (int kt = 0; kt < nk; ++kt) {
        __syncthreads();                 // stage(kt) visible; prev-buf reads done
        if (kt + 1 < nk) stage(kt + 1, cur ^ 1);
        char* ldsA = lds + cur * 32768;
        char* ldsB = ldsA + 16384;
#pragma unroll
        for (int kk = 0; kk < 2; ++kk) {
            bf16x8 af[4], bfr[4];
#pragma unroll
            for (int m = 0; m < 4; ++m) {
                int row = wr * 64 + m * 16 + lo;
                int cbyte = ((kk << 6) + (hi << 4)) ^ ((row & 7) << 4);
                af[m] = *(const bf16x8*)(ldsA + row * 128 + cbyte);
            }
#pragma unroll
            for (int n = 0; n < 4; ++n) {
                int row = wc * 64 + n * 16 + lo;
                int cbyte = ((kk << 6) + (hi << 4)) ^ ((row & 7) << 4);
                bfr[n] = *(const bf16x8*)(ldsB + row * 128 + cbyte);
            }
#pragma unroll
            for (int m = 0; m < 4; ++m)
#pragma unroll
                for (int n = 0; n < 4; ++n)
                    acc[m][n] = __builtin_amdgcn_mfma_f32_16x16x32_bf16(
                        af[m], bfr[n], acc[m][n], 0, 0, 0);
        }
        cur ^= 1;
    }

    const int rb = hi << 2;
    if (EPI == 0 || EPI == 1) {
        unsigned short* C = (unsigned short*)Cg + (size_t)z1 * cZ1 + (size_t)z2 * cZ2;
#pragma unroll
        for (int m = 0; m < 4; ++m)
#pragma unroll
            for (int n = 0; n < 4; ++n)
#pragma unroll
                for (int r = 0; r < 4; ++r) {
                    int row = m0 + wr * 64 + m * 16 + rb + r;
                    int col = n0 + wc * 64 + n * 16 + lo;
                    float v = acc[m][n][r];
                    if (EPI == 1) v = fmaxf(v, 0.f);
                    C[(size_t)row * ldc + col] = f2bf(v);
                }
    } else if (EPI == 5) {
        float* C = (float*)Cg + (size_t)z1 * cZ1 + (size_t)z2 * cZ2;
#pragma unroll
        for (int m = 0; m < 4; ++m)
#pragma unroll
            for (int n = 0; n < 4; ++n)
#pragma unroll
                for (int r = 0; r < 4; ++r) {
                    int row = m0 + wr * 64 + m * 16 + rb + r;
                    int col = n0 + wc * 64 + n * 16 + lo;
                    atomicAdd(&C[(size_t)row * ldc + col], acc[m][n][r]);
                }
    } else {  // EPI == 3: coalesced fp32 NT store via padded-LDS transpose
        float* C = (float*)Cg + (size_t)z1 * cZ1 + (size_t)z2 * cZ2;
        float* lf = (float*)lds;                 // [128][132] f32 (padded)
        __syncthreads();                         // staging LDS reads all done
#pragma unroll
        for (int m = 0; m < 4; ++m)
#pragma unroll
            for (int n = 0; n < 4; ++n)
#pragma unroll
                for (int r = 0; r < 4; ++r) {
                    int row = wr * 64 + m * 16 + rb + r;
                    int col = wc * 64 + n * 16 + lo;
                    lf[row * 132 + col] = acc[m][n][r] * scale;
                }
        __syncthreads();
#pragma unroll
        for (int i = 0; i < 16; ++i) {
            int u = i * 256 + t;
            int row = u >> 5, c4 = (u & 31) << 2;
            f32x4 v = *(f32x4*)&lf[row * 132 + c4];
            __builtin_nontemporal_store(v,
                (f32x4*)&C[(size_t)(m0 + row) * ldc + n0 + c4]);
        }
    }
}

// ---------------------------------------------------------------------------
// Fused attention, 2-phase K-pipeline, PV d-split (grid z = 2 halves):
// each wg computes full QK^T + softmax (duplicated across the 2 d-halves,
// cheap) but only 64 of 128 output d-columns -> 512 wgs, 2 wg/CU, 2 waves/SIMD
// (was 1 — latency-bound).
// ---------------------------------------------------------------------------
template<int CAUSAL>
__global__ __launch_bounds__(256)
void attn_k(const bf16* __restrict__ qkv, const bf16* __restrict__ VT,
            bf16* __restrict__ attno)
{
    __shared__ __align__(16) char ldsK[2][16384];
    __shared__ __align__(16) char ldsP[8192];
    const float SC = 0.088388347648318447f;

    const int t = threadIdx.x, w = t >> 6, lane = t & 63;
    const int lo = lane & 15, hi = lane >> 4;
    const int qb = blockIdx.x, z = blockIdx.y, dh = blockIdx.z;
    const int b = z >> 3, h = z & 7;
    const int qr0 = qb * 64 + w * 16;

    const unsigned short* Qg = (const unsigned short*)qkv + (size_t)(b * 256) * 3072 + h * 128;
    const unsigned short* Kg = Qg + 1024;
    const unsigned short* VTz = (const unsigned short*)VT + (size_t)z * 32768;

    bf16x8 qf[4];
#pragma unroll
    for (int ks = 0; ks < 4; ++ks)
        qf[ks] = *(const bf16x8*)(Qg + (size_t)(qr0 + lo) * 3072 + ks * 32 + hi * 8);

    f32x4 accO[4];
#pragma unroll
    for (int n2 = 0; n2 < 4; ++n2) accO[n2] = f32x4{0.f, 0.f, 0.f, 0.f};
    float mrun[4], lrun[4];
#pragma unroll
    for (int r = 0; r < 4; ++r) { mrun[r] = -3.0e38f; lrun[r] = 0.f; }

    auto stageK = [&](int kt, int buf) {
#pragma unroll
        for (int i = 0; i < 4; ++i) {
            int u = i * 256 + t;
            int row = u >> 4, j = u & 15;
            int sj = (j & 8) | ((j ^ row) & 7);
            load_lds16(Kg + (size_t)(kt * 64 + row) * 3072 + sj * 8,
                       ldsK[buf] + i * 4096 + w * 1024);
        }
    };

    const int nkt = CAUSAL ? (qb + 1) : 4;
    stageK(0, 0);
    int cur = 0;
    for (int kt = 0; kt < nkt; ++kt) {
        __syncthreads();
        if (kt + 1 < nkt) stageK(kt + 1, cur ^ 1);

        f32x4 s4[4];
#pragma unroll
        for (int n = 0; n < 4; ++n) s4[n] = f32x4{0.f, 0.f, 0.f, 0.f};
#pragma unroll
        for (int ks = 0; ks < 4; ++ks)
#pragma unroll
            for (int n = 0; n < 4; ++n) {
                int kr = n * 16 + lo;
                int c = ks * 4 + hi;
                int sc2 = (c & 8) | ((c ^ (kr & 7)) & 7);
                bf16x8 kf = *(const bf16x8*)(ldsK[cur] + kr * 256 + sc2 * 16);
                s4[n] = __builtin_amdgcn_mfma_f32_16x16x32_bf16(qf[ks], kf, s4[n], 0, 0, 0);
            }

        float sv[4][4];
#pragma unroll
        for (int n = 0; n < 4; ++n)
#pragma unroll
            for (int r = 0; r < 4; ++r) {
                float v = s4[n][r] * SC;
                if (CAUSAL) {
                    int kg = kt * 64 + n * 16 + lo;
                    int qg2 = qb * 64 + w * 16 + hi * 4 + r;
                    if (kg > qg2) v = -3.0e38f;
                }
                sv[n][r] = v;
            }

        float sfv[4];
#pragma unroll
        for (int r = 0; r < 4; ++r) {
            float m2 = fmaxf(fmaxf(sv[0][r], sv[1][r]), fmaxf(sv[2][r], sv[3][r]));
#pragma unroll
            for (int o = 1; o < 16; o <<= 1) m2 = fmaxf(m2, __shfl_xor(m2, o));
            float mn = fmaxf(mrun[r], m2);
            sfv[r] = __expf(mrun[r] - mn);
            mrun[r] = mn;
        }
        float p[4][4], ts[4];
#pragma unroll
        for (int r = 0; r < 4; ++r) ts[r] = 0.f;
#pragma unroll
        for (int n = 0; n < 4; ++n)
#pragma unroll
            for (int r = 0; r < 4; ++r) {
                float e = __expf(sv[n][r] - mrun[r]);
                p[n][r] = e; ts[r] += e;
            }
#pragma unroll
        for (int r = 0; r < 4; ++r) {
            float s2 = ts[r];
#pragma unroll
            for (int o = 1; o < 16; o <<= 1) s2 += __shfl_xor(s2, o);
            lrun[r] = lrun[r] * sfv[r] + s2;
        }
#pragma unroll
        for (int n2 = 0; n2 < 4; ++n2)
#pragma unroll
            for (int r = 0; r < 4; ++r) accO[n2][r] *= sfv[r];

        char* pb = ldsP + w * 2048;
#pragma unroll
        for (int n = 0; n < 4; ++n)
#pragma unroll
            for (int r = 0; r < 4; ++r) {
                int q = hi * 4 + r, k = n * 16 + lo;
                int ch = (k >> 3) ^ (q & 7);
                *(unsigned short*)(pb + q * 128 + ch * 16 + (k & 7) * 2) = f2bf(p[n][r]);
            }

        // O += P @ V for this wg's 64 d-columns
#pragma unroll
        for (int ks2 = 0; ks2 < 2; ++ks2) {
            int c2 = (ks2 * 4 + hi) ^ (lo & 7);
            bf16x8 pa = *(const bf16x8*)(pb + lo * 128 + c2 * 16);
#pragma unroll
            for (int n2 = 0; n2 < 4; ++n2) {
                int d = dh * 64 + n2 * 16 + lo;
                bf16x8 vb = *(const bf16x8*)(VTz + (size_t)d * 256 + kt * 64 + ks2 * 32 + hi * 8);
                accO[n2] = __builtin_amdgcn_mfma_f32_16x16x32_bf16(pa, vb, accO[n2], 0, 0, 0);
            }
        }
        cur ^= 1;
    }

    float inv[4];
#pragma unroll
    for (int r = 0; r < 4; ++r) inv[r] = 1.f / lrun[r];
    unsigned short* Og = (unsigned short*)attno;
#pragma unroll
    for (int n2 = 0; n2 < 4; ++n2)
#pragma unroll
        for (int r = 0; r < 4; ++r) {
            int qg2 = qb * 64 + w * 16 + hi * 4 + r;
            int d = dh * 64 + n2 * 16 + lo;
            Og[(size_t)(b * 256 + qg2) * 1024 + h * 128 + d] = f2bf(accO[n2][r] * inv[r]);
        }
}

// V (rows s at stride 3072, z=(b,h)) -> VT[z][d][s]
__global__ __launch_bounds__(256)
void vtrans_k(const bf16* __restrict__ v, bf16* __restrict__ VT)
{
    __shared__ unsigned short lds[128 * 65];
    int z = blockIdx.y;
    int b = z >> 3, hh = z & 7;
    int sc = blockIdx.x;
    const unsigned short* src = (const unsigned short*)v
        + (size_t)(b * 256 + sc * 64) * 3072 + hh * 128;
    int t = threadIdx.x;
#pragma unroll
    for (int i = 0; i < 32; ++i) {
        int lin = i * 256 + t;
        int sl = lin >> 7, d = lin & 127;
        lds[d * 65 + sl] = src[(size_t)sl * 3072 + d];
    }
    __syncthreads();
    unsigned short* dst = (unsigned short*)VT + (size_t)z * 32768 + sc * 64;
#pragma unroll
    for (int i = 0; i < 32; ++i) {
        int lin = i * 256 + t;
        int d = lin >> 6, sl = lin & 63;
        dst[(size_t)d * 256 + sl] = lds[d * 65 + sl];
    }
}

// fp32 [K][N] -> bf16 [N][K] transpose+convert, vectorized both sides:
// f32x4 NT loads (16B/lane), pad-72 LDS, ushort8 global stores (16B/lane).
DEV void wconv_tile(const float* __restrict__ W, unsigned short* __restrict__ WT,
                    int K, int N, int k0, int n0, int t, unsigned short* lds)
{
#pragma unroll
    for (int i = 0; i < 4; ++i) {
        int u = i * 256 + t;                 // f32x4 index (1024 total)
        int r = u >> 4, c4 = (u & 15) << 2;  // k-local row, n-local col
        f32x4 v = __builtin_nontemporal_load(
            (const f32x4*)&W[(size_t)(k0 + r) * N + n0 + c4]);
        lds[(c4 + 0) * 72 + r] = f2bf(v[0]);
        lds[(c4 + 1) * 72 + r] = f2bf(v[1]);
        lds[(c4 + 2) * 72 + r] = f2bf(v[2]);
        lds[(c4 + 3) * 72 + r] = f2bf(v[3]);
    }
    __syncthreads();
#pragma unroll
    for (int i = 0; i < 2; ++i) {
        int u = i * 256 + t;                 // ushort8 index (512 total)
        int r = u >> 3, c8 = (u & 7) << 3;   // n-local row, k-local col
        u16x8 v8 = *(const u16x8*)&lds[r * 72 + c8];
        *(u16x8*)&WT[(size_t)(n0 + r) * K + k0 + c8] = v8;
    }
}

__global__ __launch_bounds__(256)
void wconv_k(const float* __restrict__ W, bf16* __restrict__ WT, int K, int N)
{
    __shared__ __align__(16) unsigned short lds[64 * 72];
    size_t moff = (size_t)blockIdx.z * K * N;
    wconv_tile(W + moff, (unsigned short*)WT + moff, K, N,
               blockIdx.x * 64, blockIdx.y * 64, threadIdx.x, lds);
}

__global__ __launch_bounds__(256)
void wconv3_k(const float* __restrict__ Wa, const float* __restrict__ W1,
              const float* __restrict__ W2, bf16* __restrict__ WTa,
              bf16* __restrict__ WT1, bf16* __restrict__ WT2)
{
    __shared__ __align__(16) unsigned short lds[64 * 72];
    int bid = blockIdx.x, t = threadIdx.x;
    if (bid < 2048) {
        int mat = bid >> 8, r = bid & 255;
        size_t moff = (size_t)mat * 1048576;
        wconv_tile(Wa + moff, (unsigned short*)WTa + moff, 1024, 1024,
                   (r & 15) * 64, (r >> 4) * 64, t, lds);
    } else if (bid < 3072) {
        int idx = bid - 2048;
        wconv_tile(W1, (unsigned short*)WT1, 1024, 4096,
                   (idx & 15) * 64, (idx >> 4) * 64, t, lds);
    } else {
        int idx = bid - 3072;
        wconv_tile(W2, (unsigned short*)WT2, 4096, 1024,
                   (idx & 63) * 64, (idx >> 6) * 64, t, lds);
    }
}

__global__ __launch_bounds__(256)
void f2b_k(const float* __restrict__ in, bf16* __restrict__ out, int n4)
{
    int i = blockIdx.x * 256 + threadIdx.x;
    if (i >= n4) return;
    float4 v = ((const float4*)in)[i];
    ushort4 o;
    o.x = f2bf(v.x); o.y = f2bf(v.y); o.z = f2bf(v.z); o.w = f2bf(v.w);
    ((ushort4*)out)[i] = o;
}

__global__ __launch_bounds__(256)
void embed_k(const float* __restrict__ tok_emb, const int* __restrict__ gold,
             const float* __restrict__ sos, float* __restrict__ x)
{
    int row = blockIdx.x;
    int b = row >> 8, sq = row & 255;
    int c4 = threadIdx.x;
    float4 v;
    if (sq == 0) {
        v = ((const float4*)sos)[c4];
    } else {
        int c = c4 << 2;
        if (c < 768) {
            int tok = gold[b * 256 + sq - 1];
            v = ((const float4*)(tok_emb + (size_t)tok * 768))[c4];
        } else {
            int p = sq - 1;
            v.x = (c + 0 - 768 == p) ? 1.f : 0.f;
            v.y = (c + 1 - 768 == p) ? 1.f : 0.f;
            v.z = (c + 2 - 768 == p) ? 1.f : 0.f;
            v.w = (c + 3 - 768 == p) ? 1.f : 0.f;
        }
    }
    ((float4*)(x + (size_t)row * 1024))[c4] = v;
}

__global__ __launch_bounds__(256)
void ln_k(const float* __restrict__ x, bf16* __restrict__ out)
{
    int row = blockIdx.x;
    const float4* xr = (const float4*)(x + (size_t)row * 1024);
    float4 v = xr[threadIdx.x];
    float s = v.x + v.y + v.z + v.w;
    float ss = v.x * v.x + v.y * v.y + v.z * v.z + v.w * v.w;
    for (int o = 32; o > 0; o >>= 1) { s += __shfl_down(s, o); ss += __shfl_down(ss, o); }
    __shared__ float buf[8];
    int wv = threadIdx.x >> 6;
    if ((threadIdx.x & 63) == 0) { buf[wv] = s; buf[4 + wv] = ss; }
    __syncthreads();
    float S = buf[0] + buf[1] + buf[2] + buf[3];
    float SS = buf[4] + buf[5] + buf[6] + buf[7];
    float mean = S * (1.f / 1024.f);
    float var = SS * (1.f / 1024.f) - mean * mean;
    float rstd = rsqrtf(var + 1e-6f);
    ushort4 o;
    o.x = f2bf((v.x - mean) * rstd);
    o.y = f2bf((v.y - mean) * rstd);
    o.z = f2bf((v.z - mean) * rstd);
    o.w = f2bf((v.w - mean) * rstd);
    ((ushort4*)out)[(size_t)row * 256 + threadIdx.x] = o;
}

// ---------------------------------------------------------------------------
// Single-pass log-softmax finisher: one wg per row; whole 32000-col row in
// registers; online (max,sum) -> block reduce -> subtract -> NT store.
// ---------------------------------------------------------------------------
__global__ __launch_bounds__(512)
void lse1_k(float* __restrict__ out)
{
    const int row = blockIdx.x, t = threadIdx.x;
    f32x4* p = (f32x4*)(out + (size_t)row * 32000);   // 8000 f32x4
    f32x4 v[16];
    float m = -3.4e38f, s = 0.f;
#pragma unroll
    for (int i = 0; i < 16; ++i) {
        int idx = i * 512 + t;
        if (idx < 8000) {
            v[i] = __builtin_nontemporal_load(&p[idx]);
            float lm = fmaxf(fmaxf(v[i][0], v[i][1]), fmaxf(v[i][2], v[i][3]));
            if (lm > m) { s *= __expf(m - lm); m = lm; }
            s += __expf(v[i][0] - m) + __expf(v[i][1] - m)
               + __expf(v[i][2] - m) + __expf(v[i][3] - m);
        }
    }
    for (int o = 32; o > 0; o >>= 1) {
        float om = __shfl_down(m, o), os = __shfl_down(s, o);
        float nm = fmaxf(m, om);
        s = s * __expf(m - nm) + os * __expf(om - nm);
        m = nm;
    }
    __shared__ float bm[8], bs[8];
    __shared__ float sL;
    int wv = t >> 6;
    if ((t & 63) == 0) { bm[wv] = m; bs[wv] = s; }
    __syncthreads();
    if (t == 0) {
        float M = -3.4e38f, S = 0.f;
#pragma unroll
        for (int i = 0; i < 8; ++i) {
            float nm = fmaxf(M, bm[i]);
            S = S * __expf(M - nm) + bs[i] * __expf(bm[i] - nm);
            M = nm;
        }
        sL = M + logf(S);
    }
    __syncthreads();
    float L = sL;
#pragma unroll
    for (int i = 0; i < 16; ++i) {
        int idx = i * 512 + t;
        if (idx < 8000) {
            f32x4 w = v[i];
            w[0] -= L; w[1] -= L; w[2] -= L; w[3] -= L;
            __builtin_nontemporal_store(w, &p[idx]);
        }
    }
}

extern "C" void kernel_launch(void* const* d_in, const int* in_sizes, int n_in,
                              void* d_out, int out_size, void* d_ws, size_t ws_size,
                              hipStream_t stream)
{
    (void)in_sizes; (void)n_in; (void)out_size;
    const float* memory  = (const float*)d_in[0];
    const int*   gold    = (const int*)d_in[1];
    const float* attn_w  = (const float*)d_in[2];
    const float* ffn_w1  = (const float*)d_in[3];
    const float* ffn_w2  = (const float*)d_in[4];
    const float* tok_emb = (const float*)d_in[5];
    const float* sos     = (const float*)d_in[6];
    const float* gen_w   = (const float*)d_in[7];
    float* out = (float*)d_out;

    char* ws = (char*)d_ws;
    const size_t o_attnW = 0;                      // 16 MB
    const size_t o_ffn1W = o_attnW + 16777216;     // 8 MB
    const size_t o_ffn2W = o_ffn1W + 8388608;      // 8 MB
    const size_t o_qkv   = o_ffn2W + 8388608;      // 12.6 MB
    const size_t o_attno = o_qkv + 12582912;       // 4 MB
    const size_t o_tmp   = o_attno + 4194304;      // 29.4 MB (ffn_mid | VT)
    const size_t o_mem   = o_tmp + 29360128;       // 4 MB
    const size_t o_x     = o_mem + 4194304;        // 8 MB
    const size_t o_h     = o_x + 8388608;          // 4 MB
    const size_t NEEDED  = o_h + 4194304 + 8192;
    if (ws_size < NEEDED) return;

    bf16*  attnWT = (bf16*)(ws + o_attnW);
    bf16*  ffn1WT = (bf16*)(ws + o_ffn1W);
    bf16*  ffn2WT = (bf16*)(ws + o_ffn2W);
    bf16*  qkv    = (bf16*)(ws + o_qkv);
    bf16*  attno  = (bf16*)(ws + o_attno);
    bf16*  VT     = (bf16*)(ws + o_tmp + 25165824);
    bf16*  ffnmid = (bf16*)(ws + o_tmp);
    bf16*  memb   = (bf16*)(ws + o_mem);
    float* x      = (float*)(ws + o_x);
    bf16*  h      = (bf16*)(ws + o_h);
    bf16*  genWT  = (bf16*)(ws + 0);               // overlays dead layer-weight region

    const int BIG = 1 << 30;

    f2b_k<<<2048, 256, 0, stream>>>(memory, memb, 2048 * 1024 / 4);
    embed_k<<<2048, 256, 0, stream>>>(tok_emb, gold, sos, x);

    for (int l = 0; l < 6; ++l) {
        wconv3_k<<<4096, 256, 0, stream>>>(attn_w + (size_t)l * 8388608,
            ffn_w1 + (size_t)l * 4194304, ffn_w2 + (size_t)l * 4194304,
            attnWT, ffn1WT, ffn2WT);

        // ---- self attention ----
        ln_k<<<2048, 256, 0, stream>>>(x, h);
        gemm_k<0><<<dim3(16,24,1), 256, 0, stream>>>(h, attnWT, qkv,
            2048, 3072, 1024, 1024, 1024, 3072, 1, 0,0,0,0,0,0, 0.f, nullptr, BIG);
        vtrans_k<<<dim3(4,64), 256, 0, stream>>>(qkv + 2048, VT);
        attn_k<1><<<dim3(4,64,2), 256, 0, stream>>>(qkv, VT, attno);
        gemm_k<5><<<dim3(16,8,4), 256, 0, stream>>>(attno, attnWT + 3 * 1048576, x,
            2048, 1024, 256, 1024, 1024, 1024, 4, 0,256, 0,256, 0,0, 0.f, nullptr, BIG);

        // ---- cross attention (q from h, kv from memb — one merged launch) ----
        ln_k<<<2048, 256, 0, stream>>>(x, h);
        gemm_k<0><<<dim3(16,24,1), 256, 0, stream>>>(h, attnWT + 4 * 1048576, qkv,
            2048, 3072, 1024, 1024, 1024, 3072, 1, 0,0,0,0,0,0, 0.f, memb, 8);
        vtrans_k<<<dim3(4,64), 256, 0, stream>>>(qkv + 2048, VT);
        attn_k<0><<<dim3(4,64,2), 256, 0, stream>>>(qkv, VT, attno);
        gemm_k<5><<<dim3(16,8,4), 256, 0, stream>>>(attno, attnWT + 7 * 1048576, x,
            2048, 1024, 256, 1024, 1024, 1024, 4, 0,256, 0,256, 0,0, 0.f, nullptr, BIG);

        // ---- FFN ----
        ln_k<<<2048, 256, 0, stream>>>(x, h);
        gemm_k<1><<<dim3(16,32,1), 256, 0, stream>>>(h, ffn1WT, ffnmid,
            2048, 4096, 1024, 1024, 1024, 4096, 1, 0,0,0,0,0,0, 0.f, nullptr, BIG);
        gemm_k<5><<<dim3(16,8,4), 256, 0, stream>>>(ffnmid, ffn2WT, x,
            2048, 1024, 1024, 4096, 4096, 1024, 4, 0,1024, 0,1024, 0,0, 0.f, nullptr, BIG);
    }

    wconv_k<<<dim3(16,500,1), 256, 0, stream>>>(gen_w, genWT, 1024, 32000);
    ln_k<<<2048, 256, 0, stream>>>(x, h);
    gemm_k<3><<<dim3(16,250,1), 256, 0, stream>>>(h, genWT, out,
        2048, 32000, 1024, 1024, 1024, 32000, 1, 0,0,0,0,0,0, 1.f, nullptr, BIG);
    lse1_k<<<2048, 512, 0, stream>>>(out);
}

// Round 14
// 1581.853 us; speedup vs baseline: 1.0773x; 1.0773x over previous
//
#include <hip/hip_runtime.h>
#include <hip/hip_bf16.h>
#include <cstdint>
#include <cstddef>

using bf16 = __hip_bfloat16;
typedef __attribute__((ext_vector_type(8))) short bf16x8;
typedef __attribute__((ext_vector_type(4))) float f32x4;
typedef __attribute__((ext_vector_type(8))) unsigned short u16x8;

#define DEV static __device__ __forceinline__

DEV unsigned short f2bf(float f) {
    bf16 h = __float2bfloat16(f);
    return __builtin_bit_cast(unsigned short, h);
}

typedef const __attribute__((address_space(1))) void* as1cv;
typedef __attribute__((address_space(3))) void* as3v;

DEV void load_lds16(const void* g, void* l) {
    __builtin_amdgcn_global_load_lds((as1cv)g, (as3v)l, 16, 0, 0);
}

// ---------------------------------------------------------------------------
// Generic bf16 MFMA GEMM: C[M,N] = A[M,K] @ B^T  (B stored [N][K], k-contiguous)
// 128x128 tile, BK=64, 4 waves, 2-phase double-buffered LDS.
// EPI: 0 = store bf16; 1 = relu -> bf16;
//      3 = fp32 NT store, coalesced via padded-LDS transpose (logits);
//      5 = fp32 atomicAdd (split-K partials / residual accumulate).
// Ag2/ySplitA: blocks with by >= ySplitA read A from Ag2 (merged dual-source).
// Split-K: gridDim.z = Hdim = nchunks, aZ2/bZ2 = chunkK, Kdim = chunkK.
// ---------------------------------------------------------------------------
template<int EPI>
__global__ __launch_bounds__(256)
void gemm_k(const bf16* __restrict__ Ag, const bf16* __restrict__ Bg,
            void* __restrict__ Cg,
            int Mdim, int Ndim, int Kdim,
            int lda, int ldb, int ldc,
            int Hdim, long aZ1, long aZ2, long bZ1, long bZ2,
            long cZ1, long cZ2, float scale,
            const bf16* __restrict__ Ag2, int ySplitA)
{
    __shared__ __align__(16) char lds[67584];   // dbuf 2x32K; EPI3 reuses 128x132 f32

    const int t = threadIdx.x;
    const int wave = t >> 6, lane = t & 63;
    const int wr = wave >> 1, wc = wave & 1;
    const int lo = lane & 15, hi = lane >> 4;

    const int bx2 = blockIdx.x, by2 = blockIdx.y;
    const int m0 = bx2 * 128, n0 = by2 * 128;
    const int z = blockIdx.z;
    const int z1 = z / Hdim, z2 = z - z1 * Hdim;

    const bf16* Abase = (by2 >= ySplitA) ? Ag2 : Ag;
    const bf16* A = Abase + (size_t)z1 * aZ1 + (size_t)z2 * aZ2;
    const bf16* B = Bg + (size_t)z1 * bZ1 + (size_t)z2 * bZ2;

    f32x4 acc[4][4];
#pragma unroll
    for (int m = 0; m < 4; ++m)
#pragma unroll
        for (int n = 0; n < 4; ++n)
            acc[m][n] = f32x4{0.f, 0.f, 0.f, 0.f};

    const int nk = Kdim >> 6;

    auto stage = [&](int kt, int buf) {
        const int k0 = kt << 6;
        char* dA = lds + buf * 32768;
        char* dB = dA + 16384;
#pragma unroll
        for (int i = 0; i < 4; ++i) {
            int u = i * 256 + t;
            int row = u >> 3;
            int cb = (u & 7) ^ (row & 7);
            load_lds16(A + (size_t)(m0 + row) * lda + (k0 + cb * 8),
                       dA + i * 4096 + wave * 1024);
        }
#pragma unroll
        for (int i = 0; i < 4; ++i) {
            int u = i * 256 + t;
            int row = u >> 3;
            int cb = (u & 7) ^ (row & 7);
            load_lds16(B + (size_t)(n0 + row) * ldb + (k0 + cb * 8),
                       dB + i * 4096 + wave * 1024);
        }
    };

    stage(0, 0);
    int cur = 0;
    for (int kt = 0; kt < nk; ++kt) {
        __syncthreads();                 // stage(kt) visible; prev-buf reads done
        if (kt + 1 < nk) stage(kt + 1, cur ^ 1);
        char* ldsA = lds + cur * 32768;
        char* ldsB = ldsA + 16384;
#pragma unroll
        for (int kk = 0; kk < 2; ++kk) {
            bf16x8 af[4], bfr[4];
#pragma unroll
            for (int m = 0; m < 4; ++m) {
                int row = wr * 64 + m * 16 + lo;
                int cbyte = ((kk << 6) + (hi << 4)) ^ ((row & 7) << 4);
                af[m] = *(const bf16x8*)(ldsA + row * 128 + cbyte);
            }
#pragma unroll
            for (int n = 0; n < 4; ++n) {
                int row = wc * 64 + n * 16 + lo;
                int cbyte = ((kk << 6) + (hi << 4)) ^ ((row & 7) << 4);
                bfr[n] = *(const bf16x8*)(ldsB + row * 128 + cbyte);
            }
#pragma unroll
            for (int m = 0; m < 4; ++m)
#pragma unroll
                for (int n = 0; n < 4; ++n)
                    acc[m][n] = __builtin_amdgcn_mfma_f32_16x16x32_bf16(
                        af[m], bfr[n], acc[m][n], 0, 0, 0);
        }
        cur ^= 1;
    }

    const int rb = hi << 2;
    if (EPI == 0 || EPI == 1) {
        unsigned short* C = (unsigned short*)Cg + (size_t)z1 * cZ1 + (size_t)z2 * cZ2;
#pragma unroll
        for (int m = 0; m < 4; ++m)
#pragma unroll
            for (int n = 0; n < 4; ++n)
#pragma unroll
                for (int r = 0; r < 4; ++r) {
                    int row = m0 + wr * 64 + m * 16 + rb + r;
                    int col = n0 + wc * 64 + n * 16 + lo;
                    float v = acc[m][n][r];
                    if (EPI == 1) v = fmaxf(v, 0.f);
                    C[(size_t)row * ldc + col] = f2bf(v);
                }
    } else if (EPI == 5) {
        float* C = (float*)Cg + (size_t)z1 * cZ1 + (size_t)z2 * cZ2;
#pragma unroll
        for (int m = 0; m < 4; ++m)
#pragma unroll
            for (int n = 0; n < 4; ++n)
#pragma unroll
                for (int r = 0; r < 4; ++r) {
                    int row = m0 + wr * 64 + m * 16 + rb + r;
                    int col = n0 + wc * 64 + n * 16 + lo;
                    atomicAdd(&C[(size_t)row * ldc + col], acc[m][n][r]);
                }
    } else {  // EPI == 3: coalesced fp32 NT store via padded-LDS transpose
        float* C = (float*)Cg + (size_t)z1 * cZ1 + (size_t)z2 * cZ2;
        float* lf = (float*)lds;                 // [128][132] f32 (padded)
        __syncthreads();                         // staging LDS reads all done
#pragma unroll
        for (int m = 0; m < 4; ++m)
#pragma unroll
            for (int n = 0; n < 4; ++n)
#pragma unroll
                for (int r = 0; r < 4; ++r) {
                    int row = wr * 64 + m * 16 + rb + r;
                    int col = wc * 64 + n * 16 + lo;
                    lf[row * 132 + col] = acc[m][n][r] * scale;
                }
        __syncthreads();
#pragma unroll
        for (int i = 0; i < 16; ++i) {
            int u = i * 256 + t;
            int row = u >> 5, c4 = (u & 31) << 2;
            f32x4 v = *(f32x4*)&lf[row * 132 + c4];
            __builtin_nontemporal_store(v,
                (f32x4*)&C[(size_t)(m0 + row) * ldc + n0 + c4]);
        }
    }
}

// ---------------------------------------------------------------------------
// Fused attention, 2-phase K-pipeline (R11 config — measured best).
// ---------------------------------------------------------------------------
template<int CAUSAL>
__global__ __launch_bounds__(256)
void attn_k(const bf16* __restrict__ qkv, const bf16* __restrict__ VT,
            bf16* __restrict__ attno)
{
    __shared__ __align__(16) char ldsK[2][16384];
    __shared__ __align__(16) char ldsP[8192];
    const float SC = 0.088388347648318447f;

    const int t = threadIdx.x, w = t >> 6, lane = t & 63;
    const int lo = lane & 15, hi = lane >> 4;
    const int qb = blockIdx.x, z = blockIdx.y;
    const int b = z >> 3, h = z & 7;
    const int qr0 = qb * 64 + w * 16;

    const unsigned short* Qg = (const unsigned short*)qkv + (size_t)(b * 256) * 3072 + h * 128;
    const unsigned short* Kg = Qg + 1024;
    const unsigned short* VTz = (const unsigned short*)VT + (size_t)z * 32768;

    bf16x8 qf[4];
#pragma unroll
    for (int ks = 0; ks < 4; ++ks)
        qf[ks] = *(const bf16x8*)(Qg + (size_t)(qr0 + lo) * 3072 + ks * 32 + hi * 8);

    f32x4 accO[8];
#pragma unroll
    for (int n2 = 0; n2 < 8; ++n2) accO[n2] = f32x4{0.f, 0.f, 0.f, 0.f};
    float mrun[4], lrun[4];
#pragma unroll
    for (int r = 0; r < 4; ++r) { mrun[r] = -3.0e38f; lrun[r] = 0.f; }

    auto stageK = [&](int kt, int buf) {
#pragma unroll
        for (int i = 0; i < 4; ++i) {
            int u = i * 256 + t;
            int row = u >> 4, j = u & 15;
            int sj = (j & 8) | ((j ^ row) & 7);
            load_lds16(Kg + (size_t)(kt * 64 + row) * 3072 + sj * 8,
                       ldsK[buf] + i * 4096 + w * 1024);
        }
    };

    const int nkt = CAUSAL ? (qb + 1) : 4;
    stageK(0, 0);
    int cur = 0;
    for (int kt = 0; kt < nkt; ++kt) {
        __syncthreads();
        if (kt + 1 < nkt) stageK(kt + 1, cur ^ 1);

        f32x4 s4[4];
#pragma unroll
        for (int n = 0; n < 4; ++n) s4[n] = f32x4{0.f, 0.f, 0.f, 0.f};
#pragma unroll
        for (int ks = 0; ks < 4; ++ks)
#pragma unroll
            for (int n = 0; n < 4; ++n) {
                int kr = n * 16 + lo;
                int c = ks * 4 + hi;
                int sc2 = (c & 8) | ((c ^ (kr & 7)) & 7);
                bf16x8 kf = *(const bf16x8*)(ldsK[cur] + kr * 256 + sc2 * 16);
                s4[n] = __builtin_amdgcn_mfma_f32_16x16x32_bf16(qf[ks], kf, s4[n], 0, 0, 0);
            }

        float sv[4][4];
#pragma unroll
        for (int n = 0; n < 4; ++n)
#pragma unroll
            for (int r = 0; r < 4; ++r) {
                float v = s4[n][r] * SC;
                if (CAUSAL) {
                    int kg = kt * 64 + n * 16 + lo;
                    int qg2 = qb * 64 + w * 16 + hi * 4 + r;
                    if (kg > qg2) v = -3.0e38f;
                }
                sv[n][r] = v;
            }

        float sfv[4];
#pragma unroll
        for (int r = 0; r < 4; ++r) {
            float m2 = fmaxf(fmaxf(sv[0][r], sv[1][r]), fmaxf(sv[2][r], sv[3][r]));
#pragma unroll
            for (int o = 1; o < 16; o <<= 1) m2 = fmaxf(m2, __shfl_xor(m2, o));
            float mn = fmaxf(mrun[r], m2);
            sfv[r] = __expf(mrun[r] - mn);
            mrun[r] = mn;
        }
        float p[4][4], ts[4];
#pragma unroll
        for (int r = 0; r < 4; ++r) ts[r] = 0.f;
#pragma unroll
        for (int n = 0; n < 4; ++n)
#pragma unroll
            for (int r = 0; r < 4; ++r) {
                float e = __expf(sv[n][r] - mrun[r]);
                p[n][r] = e; ts[r] += e;
            }
#pragma unroll
        for (int r = 0; r < 4; ++r) {
            float s2 = ts[r];
#pragma unroll
            for (int o = 1; o < 16; o <<= 1) s2 += __shfl_xor(s2, o);
            lrun[r] = lrun[r] * sfv[r] + s2;
        }
#pragma unroll
        for (int n2 = 0; n2 < 8; ++n2)
#pragma unroll
            for (int r = 0; r < 4; ++r) accO[n2][r] *= sfv[r];

        char* pb = ldsP + w * 2048;
#pragma unroll
        for (int n = 0; n < 4; ++n)
#pragma unroll
            for (int r = 0; r < 4; ++r) {
                int q = hi * 4 + r, k = n * 16 + lo;
                int ch = (k >> 3) ^ (q & 7);
                *(unsigned short*)(pb + q * 128 + ch * 16 + (k & 7) * 2) = f2bf(p[n][r]);
            }

#pragma unroll
        for (int ks2 = 0; ks2 < 2; ++ks2) {
            int c2 = (ks2 * 4 + hi) ^ (lo & 7);
            bf16x8 pa = *(const bf16x8*)(pb + lo * 128 + c2 * 16);
#pragma unroll
            for (int n2 = 0; n2 < 8; ++n2) {
                int d = n2 * 16 + lo;
                bf16x8 vb = *(const bf16x8*)(VTz + (size_t)d * 256 + kt * 64 + ks2 * 32 + hi * 8);
                accO[n2] = __builtin_amdgcn_mfma_f32_16x16x32_bf16(pa, vb, accO[n2], 0, 0, 0);
            }
        }
        cur ^= 1;
    }

    float inv[4];
#pragma unroll
    for (int r = 0; r < 4; ++r) inv[r] = 1.f / lrun[r];
    unsigned short* Og = (unsigned short*)attno;
#pragma unroll
    for (int n2 = 0; n2 < 8; ++n2)
#pragma unroll
        for (int r = 0; r < 4; ++r) {
            int qg2 = qb * 64 + w * 16 + hi * 4 + r;
            int d = n2 * 16 + lo;
            Og[(size_t)(b * 256 + qg2) * 1024 + h * 128 + d] = f2bf(accO[n2][r] * inv[r]);
        }
}

// V (rows s at stride 3072, z=(b,h)) -> VT[z][d][s]
__global__ __launch_bounds__(256)
void vtrans_k(const bf16* __restrict__ v, bf16* __restrict__ VT)
{
    __shared__ unsigned short lds[128 * 65];
    int z = blockIdx.y;
    int b = z >> 3, hh = z & 7;
    int sc = blockIdx.x;
    const unsigned short* src = (const unsigned short*)v
        + (size_t)(b * 256 + sc * 64) * 3072 + hh * 128;
    int t = threadIdx.x;
#pragma unroll
    for (int i = 0; i < 32; ++i) {
        int lin = i * 256 + t;
        int sl = lin >> 7, d = lin & 127;
        lds[d * 65 + sl] = src[(size_t)sl * 3072 + d];
    }
    __syncthreads();
    unsigned short* dst = (unsigned short*)VT + (size_t)z * 32768 + sc * 64;
#pragma unroll
    for (int i = 0; i < 32; ++i) {
        int lin = i * 256 + t;
        int d = lin >> 6, sl = lin & 63;
        dst[(size_t)d * 256 + sl] = lds[d * 65 + sl];
    }
}

// fp32 [K][N] -> bf16 [N][K] transpose+convert, vectorized both sides:
// f32x4 NT loads (16B/lane), pad-72 LDS, ushort8 global stores (16B/lane).
DEV void wconv_tile(const float* __restrict__ W, unsigned short* __restrict__ WT,
                    int K, int N, int k0, int n0, int t, unsigned short* lds)
{
#pragma unroll
    for (int i = 0; i < 4; ++i) {
        int u = i * 256 + t;                 // f32x4 index (1024 total)
        int r = u >> 4, c4 = (u & 15) << 2;  // k-local row, n-local col
        f32x4 v = __builtin_nontemporal_load(
            (const f32x4*)&W[(size_t)(k0 + r) * N + n0 + c4]);
        lds[(c4 + 0) * 72 + r] = f2bf(v[0]);
        lds[(c4 + 1) * 72 + r] = f2bf(v[1]);
        lds[(c4 + 2) * 72 + r] = f2bf(v[2]);
        lds[(c4 + 3) * 72 + r] = f2bf(v[3]);
    }
    __syncthreads();
#pragma unroll
    for (int i = 0; i < 2; ++i) {
        int u = i * 256 + t;                 // ushort8 index (512 total)
        int r = u >> 3, c8 = (u & 7) << 3;   // n-local row, k-local col
        u16x8 v8 = *(const u16x8*)&lds[r * 72 + c8];
        *(u16x8*)&WT[(size_t)(n0 + r) * K + k0 + c8] = v8;
    }
}

__global__ __launch_bounds__(256)
void wconv_k(const float* __restrict__ W, bf16* __restrict__ WT, int K, int N)
{
    __shared__ __align__(16) unsigned short lds[64 * 72];
    size_t moff = (size_t)blockIdx.z * K * N;
    wconv_tile(W + moff, (unsigned short*)WT + moff, K, N,
               blockIdx.x * 64, blockIdx.y * 64, threadIdx.x, lds);
}

__global__ __launch_bounds__(256)
void wconv3_k(const float* __restrict__ Wa, const float* __restrict__ W1,
              const float* __restrict__ W2, bf16* __restrict__ WTa,
              bf16* __restrict__ WT1, bf16* __restrict__ WT2)
{
    __shared__ __align__(16) unsigned short lds[64 * 72];
    int bid = blockIdx.x, t = threadIdx.x;
    if (bid < 2048) {
        int mat = bid >> 8, r = bid & 255;
        size_t moff = (size_t)mat * 1048576;
        wconv_tile(Wa + moff, (unsigned short*)WTa + moff, 1024, 1024,
                   (r & 15) * 64, (r >> 4) * 64, t, lds);
    } else if (bid < 3072) {
        int idx = bid - 2048;
        wconv_tile(W1, (unsigned short*)WT1, 1024, 4096,
                   (idx & 15) * 64, (idx >> 4) * 64, t, lds);
    } else {
        int idx = bid - 3072;
        wconv_tile(W2, (unsigned short*)WT2, 4096, 1024,
                   (idx & 63) * 64, (idx >> 6) * 64, t, lds);
    }
}

__global__ __launch_bounds__(256)
void f2b_k(const float* __restrict__ in, bf16* __restrict__ out, int n4)
{
    int i = blockIdx.x * 256 + threadIdx.x;
    if (i >= n4) return;
    float4 v = ((const float4*)in)[i];
    ushort4 o;
    o.x = f2bf(v.x); o.y = f2bf(v.y); o.z = f2bf(v.z); o.w = f2bf(v.w);
    ((ushort4*)out)[i] = o;
}

__global__ __launch_bounds__(256)
void embed_k(const float* __restrict__ tok_emb, const int* __restrict__ gold,
             const float* __restrict__ sos, float* __restrict__ x)
{
    int row = blockIdx.x;
    int b = row >> 8, sq = row & 255;
    int c4 = threadIdx.x;
    float4 v;
    if (sq == 0) {
        v = ((const float4*)sos)[c4];
    } else {
        int c = c4 << 2;
        if (c < 768) {
            int tok = gold[b * 256 + sq - 1];
            v = ((const float4*)(tok_emb + (size_t)tok * 768))[c4];
        } else {
            int p = sq - 1;
            v.x = (c + 0 - 768 == p) ? 1.f : 0.f;
            v.y = (c + 1 - 768 == p) ? 1.f : 0.f;
            v.z = (c + 2 - 768 == p) ? 1.f : 0.f;
            v.w = (c + 3 - 768 == p) ? 1.f : 0.f;
        }
    }
    ((float4*)(x + (size_t)row * 1024))[c4] = v;
}

__global__ __launch_bounds__(256)
void ln_k(const float* __restrict__ x, bf16* __restrict__ out)
{
    int row = blockIdx.x;
    const float4* xr = (const float4*)(x + (size_t)row * 1024);
    float4 v = xr[threadIdx.x];
    float s = v.x + v.y + v.z + v.w;
    float ss = v.x * v.x + v.y * v.y + v.z * v.z + v.w * v.w;
    for (int o = 32; o > 0; o >>= 1) { s += __shfl_down(s, o); ss += __shfl_down(ss, o); }
    __shared__ float buf[8];
    int wv = threadIdx.x >> 6;
    if ((threadIdx.x & 63) == 0) { buf[wv] = s; buf[4 + wv] = ss; }
    __syncthreads();
    float S = buf[0] + buf[1] + buf[2] + buf[3];
    float SS = buf[4] + buf[5] + buf[6] + buf[7];
    float mean = S * (1.f / 1024.f);
    float var = SS * (1.f / 1024.f) - mean * mean;
    float rstd = rsqrtf(var + 1e-6f);
    ushort4 o;
    o.x = f2bf((v.x - mean) * rstd);
    o.y = f2bf((v.y - mean) * rstd);
    o.z = f2bf((v.z - mean) * rstd);
    o.w = f2bf((v.w - mean) * rstd);
    ((ushort4*)out)[(size_t)row * 256 + threadIdx.x] = o;
}

// ---------------------------------------------------------------------------
// Single-pass log-softmax finisher: one wg per row; whole 32000-col row in
// registers; online (max,sum) -> block reduce -> subtract -> NT store.
// ---------------------------------------------------------------------------
__global__ __launch_bounds__(512)
void lse1_k(float* __restrict__ out)
{
    const int row = blockIdx.x, t = threadIdx.x;
    f32x4* p = (f32x4*)(out + (size_t)row * 32000);   // 8000 f32x4
    f32x4 v[16];
    float m = -3.4e38f, s = 0.f;
#pragma unroll
    for (int i = 0; i < 16; ++i) {
        int idx = i * 512 + t;
        if (idx < 8000) {
            v[i] = __builtin_nontemporal_load(&p[idx]);
            float lm = fmaxf(fmaxf(v[i][0], v[i][1]), fmaxf(v[i][2], v[i][3]));
            if (lm > m) { s *= __expf(m - lm); m = lm; }
            s += __expf(v[i][0] - m) + __expf(v[i][1] - m)
               + __expf(v[i][2] - m) + __expf(v[i][3] - m);
        }
    }
    for (int o = 32; o > 0; o >>= 1) {
        float om = __shfl_down(m, o), os = __shfl_down(s, o);
        float nm = fmaxf(m, om);
        s = s * __expf(m - nm) + os * __expf(om - nm);
        m = nm;
    }
    __shared__ float bm[8], bs[8];
    __shared__ float sL;
    int wv = t >> 6;
    if ((t & 63) == 0) { bm[wv] = m; bs[wv] = s; }
    __syncthreads();
    if (t == 0) {
        float M = -3.4e38f, S = 0.f;
#pragma unroll
        for (int i = 0; i < 8; ++i) {
            float nm = fmaxf(M, bm[i]);
            S = S * __expf(M - nm) + bs[i] * __expf(bm[i] - nm);
            M = nm;
        }
        sL = M + logf(S);
    }
    __syncthreads();
    float L = sL;
#pragma unroll
    for (int i = 0; i < 16; ++i) {
        int idx = i * 512 + t;
        if (idx < 8000) {
            f32x4 w = v[i];
            w[0] -= L; w[1] -= L; w[2] -= L; w[3] -= L;
            __builtin_nontemporal_store(w, &p[idx]);
        }
    }
}

extern "C" void kernel_launch(void* const* d_in, const int* in_sizes, int n_in,
                              void* d_out, int out_size, void* d_ws, size_t ws_size,
                              hipStream_t stream)
{
    (void)in_sizes; (void)n_in; (void)out_size;
    const float* memory  = (const float*)d_in[0];
    const int*   gold    = (const int*)d_in[1];
    const float* attn_w  = (const float*)d_in[2];
    const float* ffn_w1  = (const float*)d_in[3];
    const float* ffn_w2  = (const float*)d_in[4];
    const float* tok_emb = (const float*)d_in[5];
    const float* sos     = (const float*)d_in[6];
    const float* gen_w   = (const float*)d_in[7];
    float* out = (float*)d_out;

    char* ws = (char*)d_ws;
    const size_t o_attnW = 0;                      // 16 MB
    const size_t o_ffn1W = o_attnW + 16777216;     // 8 MB
    const size_t o_ffn2W = o_ffn1W + 8388608;      // 8 MB
    const size_t o_qkv   = o_ffn2W + 8388608;      // 12.6 MB
    const size_t o_attno = o_qkv + 12582912;       // 4 MB
    const size_t o_tmp   = o_attno + 4194304;      // 29.4 MB (ffn_mid | VT)
    const size_t o_mem   = o_tmp + 29360128;       // 4 MB
    const size_t o_x     = o_mem + 4194304;        // 8 MB
    const size_t o_h     = o_x + 8388608;          // 4 MB
    const size_t NEEDED  = o_h + 4194304 + 8192;
    if (ws_size < NEEDED) return;

    bf16*  attnWT = (bf16*)(ws + o_attnW);
    bf16*  ffn1WT = (bf16*)(ws + o_ffn1W);
    bf16*  ffn2WT = (bf16*)(ws + o_ffn2W);
    bf16*  qkv    = (bf16*)(ws + o_qkv);
    bf16*  attno  = (bf16*)(ws + o_attno);
    bf16*  VT     = (bf16*)(ws + o_tmp + 25165824);
    bf16*  ffnmid = (bf16*)(ws + o_tmp);
    bf16*  memb   = (bf16*)(ws + o_mem);
    float* x      = (float*)(ws + o_x);
    bf16*  h      = (bf16*)(ws + o_h);
    bf16*  genWT  = (bf16*)(ws + 0);               // overlays dead layer-weight region

    const int BIG = 1 << 30;

    f2b_k<<<2048, 256, 0, stream>>>(memory, memb, 2048 * 1024 / 4);
    embed_k<<<2048, 256, 0, stream>>>(tok_emb, gold, sos, x);

    for (int l = 0; l < 6; ++l) {
        wconv3_k<<<4096, 256, 0, stream>>>(attn_w + (size_t)l * 8388608,
            ffn_w1 + (size_t)l * 4194304, ffn_w2 + (size_t)l * 4194304,
            attnWT, ffn1WT, ffn2WT);

        // ---- self attention ----
        ln_k<<<2048, 256, 0, stream>>>(x, h);
        gemm_k<0><<<dim3(16,24,1), 256, 0, stream>>>(h, attnWT, qkv,
            2048, 3072, 1024, 1024, 1024, 3072, 1, 0,0,0,0,0,0, 0.f, nullptr, BIG);
        vtrans_k<<<dim3(4,64), 256, 0, stream>>>(qkv + 2048, VT);
        attn_k<1><<<dim3(4,64), 256, 0, stream>>>(qkv, VT, attno);
        gemm_k<5><<<dim3(16,8,2), 256, 0, stream>>>(attno, attnWT + 3 * 1048576, x,
            2048, 1024, 512, 1024, 1024, 1024, 2, 0,512, 0,512, 0,0, 0.f, nullptr, BIG);

        // ---- cross attention (q from h, kv from memb — one merged launch) ----
        ln_k<<<2048, 256, 0, stream>>>(x, h);
        gemm_k<0><<<dim3(16,24,1), 256, 0, stream>>>(h, attnWT + 4 * 1048576, qkv,
            2048, 3072, 1024, 1024, 1024, 3072, 1, 0,0,0,0,0,0, 0.f, memb, 8);
        vtrans_k<<<dim3(4,64), 256, 0, stream>>>(qkv + 2048, VT);
        attn_k<0><<<dim3(4,64), 256, 0, stream>>>(qkv, VT, attno);
        gemm_k<5><<<dim3(16,8,2), 256, 0, stream>>>(attno, attnWT + 7 * 1048576, x,
            2048, 1024, 512, 1024, 1024, 1024, 2, 0,512, 0,512, 0,0, 0.f, nullptr, BIG);

        // ---- FFN ----
        ln_k<<<2048, 256, 0, stream>>>(x, h);
        gemm_k<1><<<dim3(16,32,1), 256, 0, stream>>>(h, ffn1WT, ffnmid,
            2048, 4096, 1024, 1024, 1024, 4096, 1, 0,0,0,0,0,0, 0.f, nullptr, BIG);
        gemm_k<5><<<dim3(16,8,4), 256, 0, stream>>>(ffnmid, ffn2WT, x,
            2048, 1024, 1024, 4096, 4096, 1024, 4, 0,1024, 0,1024, 0,0, 0.f, nullptr, BIG);
    }

    wconv_k<<<dim3(16,500,1), 256, 0, stream>>>(gen_w, genWT, 1024, 32000);
    ln_k<<<2048, 256, 0, stream>>>(x, h);
    gemm_k<3><<<dim3(16,250,1), 256, 0, stream>>>(h, genWT, out,
        2048, 32000, 1024, 1024, 1024, 32000, 1, 0,0,0,0,0,0, 1.f, nullptr, BIG);
    lse1_k<<<2048, 512, 0, stream>>>(out);
}

// Round 16
// 1541.951 us; speedup vs baseline: 1.1052x; 1.0259x over previous
//
#include <hip/hip_runtime.h>
#include <hip/hip_bf16.h>
#include <cstdint>
#include <cstddef>

using bf16 = __hip_bfloat16;
typedef __attribute__((ext_vector_type(8))) short bf16x8;
typedef __attribute__((ext_vector_type(4))) float f32x4;
typedef __attribute__((ext_vector_type(8))) unsigned short u16x8;

#define DEV static __device__ __forceinline__

DEV unsigned short f2bf(float f) {
    bf16 h = __float2bfloat16(f);
    return __builtin_bit_cast(unsigned short, h);
}

typedef const __attribute__((address_space(1))) void* as1cv;
typedef __attribute__((address_space(3))) void* as3v;

DEV void load_lds16(const void* g, void* l) {
    __builtin_amdgcn_global_load_lds((as1cv)g, (as3v)l, 16, 0, 0);
}

// ---------------------------------------------------------------------------
// Generic bf16 MFMA GEMM: C[M,N] = A[M,K] @ B^T  (B stored [N][K], k-contiguous)
// 128x128 tile, BK=64, 4 waves, 2-phase double-buffered LDS.
// EPI: 0 = store bf16; 1 = relu -> bf16;
//      3 = fp32 NT store, coalesced via padded-LDS transpose (logits);
//      5 = fp32 atomicAdd (split-K partials / residual accumulate);
//      6 = qkv epilogue: by<16 store bf16; by>=16 (V block) LDS-transpose and
//          write straight to VT[z][d][s] (vtrans kernel eliminated).
// Ag2/ySplitA: blocks with by >= ySplitA read A from Ag2 (merged dual-source).
// Split-K: gridDim.z = Hdim = nchunks, aZ2/bZ2 = chunkK, Kdim = chunkK.
// ---------------------------------------------------------------------------
template<int EPI>
__global__ __launch_bounds__(256)
void gemm_k(const bf16* __restrict__ Ag, const bf16* __restrict__ Bg,
            void* __restrict__ Cg,
            int Mdim, int Ndim, int Kdim,
            int lda, int ldb, int ldc,
            int Hdim, long aZ1, long aZ2, long bZ1, long bZ2,
            long cZ1, long cZ2, float scale,
            const bf16* __restrict__ Ag2, int ySplitA,
            unsigned short* __restrict__ vt)
{
    __shared__ __align__(16) char lds[67584];   // dbuf 2x32K; EPI3/6 reuse for transpose

    const int t = threadIdx.x;
    const int wave = t >> 6, lane = t & 63;
    const int wr = wave >> 1, wc = wave & 1;
    const int lo = lane & 15, hi = lane >> 4;

    const int bx2 = blockIdx.x, by2 = blockIdx.y;
    const int m0 = bx2 * 128, n0 = by2 * 128;
    const int z = blockIdx.z;
    const int z1 = z / Hdim, z2 = z - z1 * Hdim;

    const bf16* Abase = (by2 >= ySplitA) ? Ag2 : Ag;
    const bf16* A = Abase + (size_t)z1 * aZ1 + (size_t)z2 * aZ2;
    const bf16* B = Bg + (size_t)z1 * bZ1 + (size_t)z2 * bZ2;

    f32x4 acc[4][4];
#pragma unroll
    for (int m = 0; m < 4; ++m)
#pragma unroll
        for (int n = 0; n < 4; ++n)
            acc[m][n] = f32x4{0.f, 0.f, 0.f, 0.f};

    const int nk = Kdim >> 6;

    auto stage = [&](int kt, int buf) {
        const int k0 = kt << 6;
        char* dA = lds + buf * 32768;
        char* dB = dA + 16384;
#pragma unroll
        for (int i = 0; i < 4; ++i) {
            int u = i * 256 + t;
            int row = u >> 3;
            int cb = (u & 7) ^ (row & 7);
            load_lds16(A + (size_t)(m0 + row) * lda + (k0 + cb * 8),
                       dA + i * 4096 + wave * 1024);
        }
#pragma unroll
        for (int i = 0; i < 4; ++i) {
            int u = i * 256 + t;
            int row = u >> 3;
            int cb = (u & 7) ^ (row & 7);
            load_lds16(B + (size_t)(n0 + row) * ldb + (k0 + cb * 8),
                       dB + i * 4096 + wave * 1024);
        }
    };

    stage(0, 0);
    int cur = 0;
    for (int kt = 0; kt < nk; ++kt) {
        __syncthreads();                 // stage(kt) visible; prev-buf reads done
        if (kt + 1 < nk) stage(kt + 1, cur ^ 1);
        char* ldsA = lds + cur * 32768;
        char* ldsB = ldsA + 16384;
#pragma unroll
        for (int kk = 0; kk < 2; ++kk) {
            bf16x8 af[4], bfr[4];
#pragma unroll
            for (int m = 0; m < 4; ++m) {
                int row = wr * 64 + m * 16 + lo;
                int cbyte = ((kk << 6) + (hi << 4)) ^ ((row & 7) << 4);
                af[m] = *(const bf16x8*)(ldsA + row * 128 + cbyte);
            }
#pragma unroll
            for (int n = 0; n < 4; ++n) {
                int row = wc * 64 + n * 16 + lo;
                int cbyte = ((kk << 6) + (hi << 4)) ^ ((row & 7) << 4);
                bfr[n] = *(const bf16x8*)(ldsB + row * 128 + cbyte);
            }
#pragma unroll
            for (int m = 0; m < 4; ++m)
#pragma unroll
                for (int n = 0; n < 4; ++n)
                    acc[m][n] = __builtin_amdgcn_mfma_f32_16x16x32_bf16(
                        af[m], bfr[n], acc[m][n], 0, 0, 0);
        }
        cur ^= 1;
    }

    const int rb = hi << 2;
    if (EPI == 0 || EPI == 1) {
        unsigned short* C = (unsigned short*)Cg + (size_t)z1 * cZ1 + (size_t)z2 * cZ2;
#pragma unroll
        for (int m = 0; m < 4; ++m)
#pragma unroll
            for (int n = 0; n < 4; ++n)
#pragma unroll
                for (int r = 0; r < 4; ++r) {
                    int row = m0 + wr * 64 + m * 16 + rb + r;
                    int col = n0 + wc * 64 + n * 16 + lo;
                    float v = acc[m][n][r];
                    if (EPI == 1) v = fmaxf(v, 0.f);
                    C[(size_t)row * ldc + col] = f2bf(v);
                }
    } else if (EPI == 5) {
        float* C = (float*)Cg + (size_t)z1 * cZ1 + (size_t)z2 * cZ2;
#pragma unroll
        for (int m = 0; m < 4; ++m)
#pragma unroll
            for (int n = 0; n < 4; ++n)
#pragma unroll
                for (int r = 0; r < 4; ++r) {
                    int row = m0 + wr * 64 + m * 16 + rb + r;
                    int col = n0 + wc * 64 + n * 16 + lo;
                    atomicAdd(&C[(size_t)row * ldc + col], acc[m][n][r]);
                }
    } else if (EPI == 3) {  // coalesced fp32 NT store via padded-LDS transpose
        float* C = (float*)Cg + (size_t)z1 * cZ1 + (size_t)z2 * cZ2;
        float* lf = (float*)lds;                 // [128][132] f32 (padded)
        __syncthreads();                         // staging LDS reads all done
#pragma unroll
        for (int m = 0; m < 4; ++m)
#pragma unroll
            for (int n = 0; n < 4; ++n)
#pragma unroll
                for (int r = 0; r < 4; ++r) {
                    int row = wr * 64 + m * 16 + rb + r;
                    int col = wc * 64 + n * 16 + lo;
                    lf[row * 132 + col] = acc[m][n][r] * scale;
                }
        __syncthreads();
#pragma unroll
        for (int i = 0; i < 16; ++i) {
            int u = i * 256 + t;
            int row = u >> 5, c4 = (u & 31) << 2;
            f32x4 v = *(f32x4*)&lf[row * 132 + c4];
            __builtin_nontemporal_store(v,
                (f32x4*)&C[(size_t)(m0 + row) * ldc + n0 + c4]);
        }
    } else {  // EPI == 6: qkv epilogue with V-block transpose to VT
        if (by2 < 16) {
            unsigned short* C = (unsigned short*)Cg;
#pragma unroll
            for (int m = 0; m < 4; ++m)
#pragma unroll
                for (int n = 0; n < 4; ++n)
#pragma unroll
                    for (int r = 0; r < 4; ++r) {
                        int row = m0 + wr * 64 + m * 16 + rb + r;
                        int col = n0 + wc * 64 + n * 16 + lo;
                        C[(size_t)row * ldc + col] = f2bf(acc[m][n][r]);
                    }
        } else {
            // V block: col-2048 = h*128 + d with h = by2-16; tile rows are
            // (b, s_local) with b = m0/256, s0 = m0%256. Transpose in LDS
            // ([d][s], pad 136 u16), then write VT[z=b*8+h][d][s0..s0+128)
            // in 16B coalesced chunks. Tile = 128d x 128s = 2048 u16x8 units.
            unsigned short* lT = (unsigned short*)lds;   // [128][136]
            __syncthreads();                             // staging reads done
#pragma unroll
            for (int m = 0; m < 4; ++m)
#pragma unroll
                for (int n = 0; n < 4; ++n)
#pragma unroll
                    for (int r = 0; r < 4; ++r) {
                        int s_local = wr * 64 + m * 16 + rb + r;
                        int d = wc * 64 + n * 16 + lo;
                        lT[d * 136 + s_local] = f2bf(acc[m][n][r]);
                    }
            __syncthreads();
            int hh = by2 - 16, b = m0 >> 8, s0 = m0 & 255;
            unsigned short* dst = vt + (size_t)(b * 8 + hh) * 32768 + s0;
#pragma unroll
            for (int i = 0; i < 8; ++i) {                // 2048 units total
                int u = i * 256 + t;
                int d = u >> 4, sc = (u & 15) << 3;
                u16x8 v8 = *(const u16x8*)&lT[d * 136 + sc];
                *(u16x8*)&dst[d * 256 + sc] = v8;
            }
        }
    }
}

// ---------------------------------------------------------------------------
// Fused attention, 2-phase K-pipeline (R11/R13 config — measured best).
// ---------------------------------------------------------------------------
template<int CAUSAL>
__global__ __launch_bounds__(256)
void attn_k(const bf16* __restrict__ qkv, const bf16* __restrict__ VT,
            bf16* __restrict__ attno)
{
    __shared__ __align__(16) char ldsK[2][16384];
    __shared__ __align__(16) char ldsP[8192];
    const float SC = 0.088388347648318447f;

    const int t = threadIdx.x, w = t >> 6, lane = t & 63;
    const int lo = lane & 15, hi = lane >> 4;
    const int qb = blockIdx.x, z = blockIdx.y;
    const int b = z >> 3, h = z & 7;
    const int qr0 = qb * 64 + w * 16;

    const unsigned short* Qg = (const unsigned short*)qkv + (size_t)(b * 256) * 3072 + h * 128;
    const unsigned short* Kg = Qg + 1024;
    const unsigned short* VTz = (const unsigned short*)VT + (size_t)z * 32768;

    bf16x8 qf[4];
#pragma unroll
    for (int ks = 0; ks < 4; ++ks)
        qf[ks] = *(const bf16x8*)(Qg + (size_t)(qr0 + lo) * 3072 + ks * 32 + hi * 8);

    f32x4 accO[8];
#pragma unroll
    for (int n2 = 0; n2 < 8; ++n2) accO[n2] = f32x4{0.f, 0.f, 0.f, 0.f};
    float mrun[4], lrun[4];
#pragma unroll
    for (int r = 0; r < 4; ++r) { mrun[r] = -3.0e38f; lrun[r] = 0.f; }

    auto stageK = [&](int kt, int buf) {
#pragma unroll
        for (int i = 0; i < 4; ++i) {
            int u = i * 256 + t;
            int row = u >> 4, j = u & 15;
            int sj = (j & 8) | ((j ^ row) & 7);
            load_lds16(Kg + (size_t)(kt * 64 + row) * 3072 + sj * 8,
                       ldsK[buf] + i * 4096 + w * 1024);
        }
    };

    const int nkt = CAUSAL ? (qb + 1) : 4;
    stageK(0, 0);
    int cur = 0;
    for (int kt = 0; kt < nkt; ++kt) {
        __syncthreads();
        if (kt + 1 < nkt) stageK(kt + 1, cur ^ 1);

        f32x4 s4[4];
#pragma unroll
        for (int n = 0; n < 4; ++n) s4[n] = f32x4{0.f, 0.f, 0.f, 0.f};
#pragma unroll
        for (int ks = 0; ks < 4; ++ks)
#pragma unroll
            for (int n = 0; n < 4; ++n) {
                int kr = n * 16 + lo;
                int c = ks * 4 + hi;
                int sc2 = (c & 8) | ((c ^ (kr & 7)) & 7);
                bf16x8 kf = *(const bf16x8*)(ldsK[cur] + kr * 256 + sc2 * 16);
                s4[n] = __builtin_amdgcn_mfma_f32_16x16x32_bf16(qf[ks], kf, s4[n], 0, 0, 0);
            }

        float sv[4][4];
#pragma unroll
        for (int n = 0; n < 4; ++n)
#pragma unroll
            for (int r = 0; r < 4; ++r) {
                float v = s4[n][r] * SC;
                if (CAUSAL) {
                    int kg = kt * 64 + n * 16 + lo;
                    int qg2 = qb * 64 + w * 16 + hi * 4 + r;
                    if (kg > qg2) v = -3.0e38f;
                }
                sv[n][r] = v;
            }

        float sfv[4];
#pragma unroll
        for (int r = 0; r < 4; ++r) {
            float m2 = fmaxf(fmaxf(sv[0][r], sv[1][r]), fmaxf(sv[2][r], sv[3][r]));
#pragma unroll
            for (int o = 1; o < 16; o <<= 1) m2 = fmaxf(m2, __shfl_xor(m2, o));
            float mn = fmaxf(mrun[r], m2);
            sfv[r] = __expf(mrun[r] - mn);
            mrun[r] = mn;
        }
        float p[4][4], ts[4];
#pragma unroll
        for (int r = 0; r < 4; ++r) ts[r] = 0.f;
#pragma unroll
        for (int n = 0; n < 4; ++n)
#pragma unroll
            for (int r = 0; r < 4; ++r) {
                float e = __expf(sv[n][r] - mrun[r]);
                p[n][r] = e; ts[r] += e;
            }
#pragma unroll
        for (int r = 0; r < 4; ++r) {
            float s2 = ts[r];
#pragma unroll
            for (int o = 1; o < 16; o <<= 1) s2 += __shfl_xor(s2, o);
            lrun[r] = lrun[r] * sfv[r] + s2;
        }
#pragma unroll
        for (int n2 = 0; n2 < 8; ++n2)
#pragma unroll
            for (int r = 0; r < 4; ++r) accO[n2][r] *= sfv[r];

        char* pb = ldsP + w * 2048;
#pragma unroll
        for (int n = 0; n < 4; ++n)
#pragma unroll
            for (int r = 0; r < 4; ++r) {
                int q = hi * 4 + r, k = n * 16 + lo;
                int ch = (k >> 3) ^ (q & 7);
                *(unsigned short*)(pb + q * 128 + ch * 16 + (k & 7) * 2) = f2bf(p[n][r]);
            }

#pragma unroll
        for (int ks2 = 0; ks2 < 2; ++ks2) {
            int c2 = (ks2 * 4 + hi) ^ (lo & 7);
            bf16x8 pa = *(const bf16x8*)(pb + lo * 128 + c2 * 16);
#pragma unroll
            for (int n2 = 0; n2 < 8; ++n2) {
                int d = n2 * 16 + lo;
                bf16x8 vb = *(const bf16x8*)(VTz + (size_t)d * 256 + kt * 64 + ks2 * 32 + hi * 8);
                accO[n2] = __builtin_amdgcn_mfma_f32_16x16x32_bf16(pa, vb, accO[n2], 0, 0, 0);
            }
        }
        cur ^= 1;
    }

    float inv[4];
#pragma unroll
    for (int r = 0; r < 4; ++r) inv[r] = 1.f / lrun[r];
    unsigned short* Og = (unsigned short*)attno;
#pragma unroll
    for (int n2 = 0; n2 < 8; ++n2)
#pragma unroll
        for (int r = 0; r < 4; ++r) {
            int qg2 = qb * 64 + w * 16 + hi * 4 + r;
            int d = n2 * 16 + lo;
            Og[(size_t)(b * 256 + qg2) * 1024 + h * 128 + d] = f2bf(accO[n2][r] * inv[r]);
        }
}

// fp32 [K][N] -> bf16 [N][K] transpose+convert, vectorized both sides:
// f32x4 NT loads (16B/lane), pad-72 LDS, ushort8 global stores (16B/lane).
DEV void wconv_tile(const float* __restrict__ W, unsigned short* __restrict__ WT,
                    int K, int N, int k0, int n0, int t, unsigned short* lds)
{
#pragma unroll
    for (int i = 0; i < 4; ++i) {
        int u = i * 256 + t;                 // f32x4 index (1024 total)
        int r = u >> 4, c4 = (u & 15) << 2;  // k-local row, n-local col
        f32x4 v = __builtin_nontemporal_load(
            (const f32x4*)&W[(size_t)(k0 + r) * N + n0 + c4]);
        lds[(c4 + 0) * 72 + r] = f2bf(v[0]);
        lds[(c4 + 1) * 72 + r] = f2bf(v[1]);
        lds[(c4 + 2) * 72 + r] = f2bf(v[2]);
        lds[(c4 + 3) * 72 + r] = f2bf(v[3]);
    }
    __syncthreads();
#pragma unroll
    for (int i = 0; i < 2; ++i) {
        int u = i * 256 + t;                 // ushort8 index (512 total)
        int r = u >> 3, c8 = (u & 7) << 3;   // n-local row, k-local col
        u16x8 v8 = *(const u16x8*)&lds[r * 72 + c8];
        *(u16x8*)&WT[(size_t)(n0 + r) * K + k0 + c8] = v8;
    }
}

__global__ __launch_bounds__(256)
void wconv_k(const float* __restrict__ W, bf16* __restrict__ WT, int K, int N)
{
    __shared__ __align__(16) unsigned short lds[64 * 72];
    size_t moff = (size_t)blockIdx.z * K * N;
    wconv_tile(W + moff, (unsigned short*)WT + moff, K, N,
               blockIdx.x * 64, blockIdx.y * 64, threadIdx.x, lds);
}

__global__ __launch_bounds__(256)
void wconv3_k(const float* __restrict__ Wa, const float* __restrict__ W1,
              const float* __restrict__ W2, bf16* __restrict__ WTa,
              bf16* __restrict__ WT1, bf16* __restrict__ WT2)
{
    __shared__ __align__(16) unsigned short lds[64 * 72];
    int bid = blockIdx.x, t = threadIdx.x;
    if (bid < 2048) {
        int mat = bid >> 8, r = bid & 255;
        size_t moff = (size_t)mat * 1048576;
        wconv_tile(Wa + moff, (unsigned short*)WTa + moff, 1024, 1024,
                   (r & 15) * 64, (r >> 4) * 64, t, lds);
    } else if (bid < 3072) {
        int idx = bid - 2048;
        wconv_tile(W1, (unsigned short*)WT1, 1024, 4096,
                   (idx & 15) * 64, (idx >> 4) * 64, t, lds);
    } else {
        int idx = bid - 3072;
        wconv_tile(W2, (unsigned short*)WT2, 4096, 1024,
                   (idx & 63) * 64, (idx >> 6) * 64, t, lds);
    }
}

__global__ __launch_bounds__(256)
void f2b_k(const float* __restrict__ in, bf16* __restrict__ out, int n4)
{
    int i = blockIdx.x * 256 + threadIdx.x;
    if (i >= n4) return;
    float4 v = ((const float4*)in)[i];
    ushort4 o;
    o.x = f2bf(v.x); o.y = f2bf(v.y); o.z = f2bf(v.z); o.w = f2bf(v.w);
    ((ushort4*)out)[i] = o;
}

__global__ __launch_bounds__(256)
void embed_k(const float* __restrict__ tok_emb, const int* __restrict__ gold,
             const float* __restrict__ sos, float* __restrict__ x)
{
    int row = blockIdx.x;
    int b = row >> 8, sq = row & 255;
    int c4 = threadIdx.x;
    float4 v;
    if (sq == 0) {
        v = ((const float4*)sos)[c4];
    } else {
        int c = c4 << 2;
        if (c < 768) {
            int tok = gold[b * 256 + sq - 1];
            v = ((const float4*)(tok_emb + (size_t)tok * 768))[c4];
        } else {
            int p = sq - 1;
            v.x = (c + 0 - 768 == p) ? 1.f : 0.f;
            v.y = (c + 1 - 768 == p) ? 1.f : 0.f;
            v.z = (c + 2 - 768 == p) ? 1.f : 0.f;
            v.w = (c + 3 - 768 == p) ? 1.f : 0.f;
        }
    }
    ((float4*)(x + (size_t)row * 1024))[c4] = v;
}

__global__ __launch_bounds__(256)
void ln_k(const float* __restrict__ x, bf16* __restrict__ out)
{
    int row = blockIdx.x;
    const float4* xr = (const float4*)(x + (size_t)row * 1024);
    float4 v = xr[threadIdx.x];
    float s = v.x + v.y + v.z + v.w;
    float ss = v.x * v.x + v.y * v.y + v.z * v.z + v.w * v.w;
    for (int o = 32; o > 0; o >>= 1) { s += __shfl_down(s, o); ss += __shfl_down(ss, o); }
    __shared__ float buf[8];
    int wv = threadIdx.x >> 6;
    if ((threadIdx.x & 63) == 0) { buf[wv] = s; buf[4 + wv] = ss; }
    __syncthreads();
    float S = buf[0] + buf[1] + buf[2] + buf[3];
    float SS = buf[4] + buf[5] + buf[6] + buf[7];
    float mean = S * (1.f / 1024.f);
    float var = SS * (1.f / 1024.f) - mean * mean;
    float rstd = rsqrtf(var + 1e-6f);
    ushort4 o;
    o.x = f2bf((v.x - mean) * rstd);
    o.y = f2bf((v.y - mean) * rstd);
    o.z = f2bf((v.z - mean) * rstd);
    o.w = f2bf((v.w - mean) * rstd);
    ((ushort4*)out)[(size_t)row * 256 + threadIdx.x] = o;
}

// ---------------------------------------------------------------------------
// Single-pass log-softmax finisher: one wg per row; whole 32000-col row in
// registers; online (max,sum) -> block reduce -> subtract -> NT store.
// ---------------------------------------------------------------------------
__global__ __launch_bounds__(512)
void lse1_k(float* __restrict__ out)
{
    const int row = blockIdx.x, t = threadIdx.x;
    f32x4* p = (f32x4*)(out + (size_t)row * 32000);   // 8000 f32x4
    f32x4 v[16];
    float m = -3.4e38f, s = 0.f;
#pragma unroll
    for (int i = 0; i < 16; ++i) {
        int idx = i * 512 + t;
        if (idx < 8000) {
            v[i] = __builtin_nontemporal_load(&p[idx]);
            float lm = fmaxf(fmaxf(v[i][0], v[i][1]), fmaxf(v[i][2], v[i][3]));
            if (lm > m) { s *= __expf(m - lm); m = lm; }
            s += __expf(v[i][0] - m) + __expf(v[i][1] - m)
               + __expf(v[i][2] - m) + __expf(v[i][3] - m);
        }
    }
    for (int o = 32; o > 0; o >>= 1) {
        float om = __shfl_down(m, o), os = __shfl_down(s, o);
        float nm = fmaxf(m, om);
        s = s * __expf(m - nm) + os * __expf(om - nm);
        m = nm;
    }
    __shared__ float bm[8], bs[8];
    __shared__ float sL;
    int wv = t >> 6;
    if ((t & 63) == 0) { bm[wv] = m; bs[wv] = s; }
    __syncthreads();
    if (t == 0) {
        float M = -3.4e38f, S = 0.f;
#pragma unroll
        for (int i = 0; i < 8; ++i) {
            float nm = fmaxf(M, bm[i]);
            S = S * __expf(M - nm) + bs[i] * __expf(bm[i] - nm);
            M = nm;
        }
        sL = M + logf(S);
    }
    __syncthreads();
    float L = sL;
#pragma unroll
    for (int i = 0; i < 16; ++i) {
        int idx = i * 512 + t;
        if (idx < 8000) {
            f32x4 w = v[i];
            w[0] -= L; w[1] -= L; w[2] -= L; w[3] -= L;
            __builtin_nontemporal_store(w, &p[idx]);
        }
    }
}

extern "C" void kernel_launch(void* const* d_in, const int* in_sizes, int n_in,
                              void* d_out, int out_size, void* d_ws, size_t ws_size,
                              hipStream_t stream)
{
    (void)in_sizes; (void)n_in; (void)out_size;
    const float* memory  = (const float*)d_in[0];
    const int*   gold    = (const int*)d_in[1];
    const float* attn_w  = (const float*)d_in[2];
    const float* ffn_w1  = (const float*)d_in[3];
    const float* ffn_w2  = (const float*)d_in[4];
    const float* tok_emb = (const float*)d_in[5];
    const float* sos     = (const float*)d_in[6];
    const float* gen_w   = (const float*)d_in[7];
    float* out = (float*)d_out;

    char* ws = (char*)d_ws;
    const size_t o_attnW = 0;                      // 16 MB
    const size_t o_ffn1W = o_attnW + 16777216;     // 8 MB
    const size_t o_ffn2W = o_ffn1W + 8388608;      // 8 MB
    const size_t o_qkv   = o_ffn2W + 8388608;      // 12.6 MB
    const size_t o_attno = o_qkv + 12582912;       // 4 MB
    const size_t o_tmp   = o_attno + 4194304;      // 29.4 MB (ffn_mid | VT)
    const size_t o_mem   = o_tmp + 29360128;       // 4 MB
    const size_t o_x     = o_mem + 4194304;        // 8 MB
    const size_t o_h     = o_x + 8388608;          // 4 MB
    const size_t NEEDED  = o_h + 4194304 + 8192;
    if (ws_size < NEEDED) return;

    bf16*  attnWT = (bf16*)(ws + o_attnW);
    bf16*  ffn1WT = (bf16*)(ws + o_ffn1W);
    bf16*  ffn2WT = (bf16*)(ws + o_ffn2W);
    bf16*  qkv    = (bf16*)(ws + o_qkv);
    bf16*  attno  = (bf16*)(ws + o_attno);
    bf16*  VT     = (bf16*)(ws + o_tmp + 25165824);
    bf16*  ffnmid = (bf16*)(ws + o_tmp);
    bf16*  memb   = (bf16*)(ws + o_mem);
    float* x      = (float*)(ws + o_x);
    bf16*  h      = (bf16*)(ws + o_h);
    bf16*  genWT  = (bf16*)(ws + 0);               // overlays dead layer-weight region

    const int BIG = 1 << 30;
    unsigned short* VTu = (unsigned short*)VT;

    f2b_k<<<2048, 256, 0, stream>>>(memory, memb, 2048 * 1024 / 4);
    embed_k<<<2048, 256, 0, stream>>>(tok_emb, gold, sos, x);

    for (int l = 0; l < 6; ++l) {
        wconv3_k<<<4096, 256, 0, stream>>>(attn_w + (size_t)l * 8388608,
            ffn_w1 + (size_t)l * 4194304, ffn_w2 + (size_t)l * 4194304,
            attnWT, ffn1WT, ffn2WT);

        // ---- self attention (V transposed to VT in qkv GEMM epilogue) ----
        ln_k<<<2048, 256, 0, stream>>>(x, h);
        gemm_k<6><<<dim3(16,24,1), 256, 0, stream>>>(h, attnWT, qkv,
            2048, 3072, 1024, 1024, 1024, 3072, 1, 0,0,0,0,0,0, 0.f, nullptr, BIG, VTu);
        attn_k<1><<<dim3(4,64), 256, 0, stream>>>(qkv, VT, attno);
        gemm_k<5><<<dim3(16,8,2), 256, 0, stream>>>(attno, attnWT + 3 * 1048576, x,
            2048, 1024, 512, 1024, 1024, 1024, 2, 0,512, 0,512, 0,0, 0.f, nullptr, BIG, nullptr);

        // ---- cross attention (q from h, kv from memb — one merged launch) ----
        ln_k<<<2048, 256, 0, stream>>>(x, h);
        gemm_k<6><<<dim3(16,24,1), 256, 0, stream>>>(h, attnWT + 4 * 1048576, qkv,
            2048, 3072, 1024, 1024, 1024, 3072, 1, 0,0,0,0,0,0, 0.f, memb, 8, VTu);
        attn_k<0><<<dim3(4,64), 256, 0, stream>>>(qkv, VT, attno);
        gemm_k<5><<<dim3(16,8,2), 256, 0, stream>>>(attno, attnWT + 7 * 1048576, x,
            2048, 1024, 512, 1024, 1024, 1024, 2, 0,512, 0,512, 0,0, 0.f, nullptr, BIG, nullptr);

        // ---- FFN ----
        ln_k<<<2048, 256, 0, stream>>>(x, h);
        gemm_k<1><<<dim3(16,32,1), 256, 0, stream>>>(h, ffn1WT, ffnmid,
            2048, 4096, 1024, 1024, 1024, 4096, 1, 0,0,0,0,0,0, 0.f, nullptr, BIG, nullptr);
        gemm_k<5><<<dim3(16,8,4), 256, 0, stream>>>(ffnmid, ffn2WT, x,
            2048, 1024, 1024, 4096, 4096, 1024, 4, 0,1024, 0,1024, 0,0, 0.f, nullptr, BIG, nullptr);
    }

    wconv_k<<<dim3(16,500,1), 256, 0, stream>>>(gen_w, genWT, 1024, 32000);
    ln_k<<<2048, 256, 0, stream>>>(x, h);
    gemm_k<3><<<dim3(16,250,1), 256, 0, stream>>>(h, genWT, out,
        2048, 32000, 1024, 1024, 1024, 32000, 1, 0,0,0,0,0,0, 1.f, nullptr, BIG, nullptr);
    lse1_k<<<2048, 512, 0, stream>>>(out);
}